// Round 17
// baseline (120.643 us; speedup 1.0000x reference)
//
#include <hip/hip_runtime.h>
#include <stdint.h>

#define NSTEP 365
#define NGRID 4000
#define CAPMIN 0.00125f
#define SMINV 0.0001f
#define PSTR_DW (NGRID * 88)
#define XSTR_DW (NGRID * 3)

// LDS layout (dwords), total 14720 dw = 58880 B:
//   raw ring:     4 regions x 5 slots x 384 = 7680   [0, 7680)
//   derived ring: 2 regions x 5 slots x 640 = 6400   [7680, 14080)
//   smq staging:  5 x 64 = 320                       [14080, 14400)
//   sme staging:  5 x 64 = 320                       [14400, 14720)
#define RAW_SLOT 384
#define RAW_REG  (5 * RAW_SLOT)
#define DER_BASE 7680
#define DER_SLOT 640            // 5 float2 rows x 64 lanes
#define DER_REG  (5 * DER_SLOT)
#define SMQ_BASE 14080
#define SME_BASE 14400

typedef __attribute__((address_space(3))) uint32_t lds_u32_t;
typedef __attribute__((address_space(1))) uint32_t glb_u32_t;

__device__ __forceinline__ void dma4(const float* g, float* l) {
    __builtin_amdgcn_global_load_lds((const glb_u32_t*)(const void*)g,
                                     (lds_u32_t*)(void*)l, 4, 0, 0);
}

__device__ __forceinline__ float frcp(float x) { return __builtin_amdgcn_rcpf(x); }
__device__ __forceinline__ float fexp2(float x) { return __builtin_amdgcn_exp2f(x); }
__device__ __forceinline__ float flog2(float x) { return __builtin_amdgcn_logf(x); }

__device__ __forceinline__ void issue_slot(const float* pp, const float* px,
                                           int t, float* dst) {
    const float* pj = pp + (size_t)t * PSTR_DW;
    dma4(pj,      dst);
    dma4(pj + 8,  dst + 64);
    dma4(pj + 16, dst + 128);
    dma4(pj + 24, dst + 192);
    dma4(pj + 32, dst + 256);
    dma4(px + (size_t)t * XSTR_DW, dst + 320);
}

// ---- state wave: hoisted reads; raw (c0,kuz,P,Ep) + 5 derived float2 rows ----
#define RDS(j)                                                               \
    const float  c0_##j = rreg[(j) * RAW_SLOT + lane];                       \
    const float  kz_##j = rreg[(j) * RAW_SLOT + 256 + lane];                 \
    const float  Pp_##j = rreg[(j) * RAW_SLOT + 320 + gl3];                  \
    const float  Ee_##j = rreg[(j) * RAW_SLOT + 322 + gl3];                  \
    const float2 dA_##j = dreg[(j) * 320 + lane];          /* 1/uztwm, 1/uzfwm */\
    const float2 dB_##j = dreg[(j) * 320 +  64 + lane];    /* hmean, lztwm   */\
    const float2 dC_##j = dreg[(j) * 320 + 128 + lane];    /* 1/lztwm, pbase */\
    const float2 dD_##j = dreg[(j) * 320 + 192 + lane];    /* lzfwpm, lzfwsm */\
    const float2 dE_##j = dreg[(j) * 320 + 256 + lane];    /* pz, 1/defmax   */

#define STEP(j) do {                                                         \
    const float inv_uztwm = dA_##j.x, inv_uzfwm = dA_##j.y;                  \
    const float hmean = dB_##j.x, lztwm = dB_##j.y;                          \
    const float inv_lztwm = dC_##j.x, pbase = dC_##j.y;                      \
    const float lzfwpm = dD_##j.x, lzfwsm = dD_##j.y;                        \
    const float pz = dE_##j.x, inv_defmax = dE_##j.y;                        \
    const float Ep = Ee_##j, kuz = kz_##j;                                   \
    const float qdir = c0_##j * Pp_##j;                                      \
    const float peff = Pp_##j - qdir;                                        \
    const float r1 = S1 * inv_uztwm;                                         \
    const float r2 = S2 * inv_uzfwm;                                         \
    const float euztw = fminf(r1 * Ep, S1);                                  \
    const float twexu = (r1 >= 1.0f) ? peff : 0.0f;                          \
    const float qsur  = (r2 >= 1.0f) ? twexu : 0.0f;                         \
    const float rd = r2 - r1;                                                \
    const float ru = (rd > 0.0f) ? rd * hmean : 0.0f;                        \
    const float qint = kuz * S2;                                             \
    const float euzfw = fminf(fmaxf(0.0f, Ep - euztw), S2);                  \
    const float t3 = lztwm - S3, t4 = lzfwpm - S4, t5 = lzfwsm - S5;         \
    const float deficit = fmaxf(1e-8f, t3) + fmaxf(1e-8f, t4)                \
                        + fmaxf(1e-8f, t5);                                  \
    const float powterm = fexp2(e1 * flog2(deficit * inv_defmax));           \
    const float pc = fminf((pbase + pz * powterm) * r2, S2);                 \
    const float pctw = pfree1m * pc;                                         \
    const float ev3 = fmaxf(0.0f, Ep - euztw - euzfw);                       \
    const float elztw = fminf(S3 * inv_lztwm * ev3, S3);                     \
    const float twexl = (S3 >= lztwm) ? pctw : 0.0f;                         \
    const float aa = fmaxf(0.0f, t4) * lzfwsm;                               \
    const float bb = fmaxf(0.0f, t5) * lzfwpm;                               \
    const float den = aa + bb;                                               \
    const float pm = lzfwpm + lzfwsm;                                        \
    const float fp = ((den > 0.0f) ? aa : lzfwpm)                            \
                   * frcp((den > 0.0f) ? den : pm);                          \
    const float fs = 1.0f - fp;                                              \
    const float pcp = pfree * pc;                                            \
    const float twexlp = fp * twexl, twexls = fs * twexl;                    \
    const float pcfwp = fp * pcp, pcfws = fs * pcp;                          \
    const bool rlm = S3 * pm < (S4 + S5) * lztwm;                            \
    const float rlp = rlm ? (S4 * lztwm - S3 * lzfwpm) * inv_defmax : 0.0f;  \
    const float rls = rlm ? (S5 * lztwm - S3 * lzfwsm) * inv_defmax : 0.0f;  \
    const float qbfp = klzp * S4, qbfs = klzs * S5;                          \
    S1 = fmaxf(S1 + peff + ru - euztw - twexu, SMINV);                       \
    S2 = fmaxf(S2 + twexu - euzfw - qsur - qint - ru - pc, SMINV);           \
    S3 = fmaxf(S3 + pctw + rlp + rls - elztw - twexl, SMINV);                \
    S4 = fmaxf(S4 + twexlp + pcfwp - rlp - qbfp, SMINV);                     \
    S5 = fmaxf(S5 + twexls + pcfws - rls - qbfs, SMINV);                     \
    smq[(j) * 64 + lane] = qdir + qsur + qint + qbfp + qbfs;                 \
    sme[(j) * 64 + lane] = euztw + euzfw + elztw;                            \
} while (0)

__global__ __launch_bounds__(192, 1) void sacsma_kernel(
    const float* __restrict__ x,     // [NSTEP][NGRID][3]
    const float* __restrict__ par,   // [NSTEP][NGRID][11][8]
    float* __restrict__ out)         // [NSTEP][NGRID][2]
{
    __shared__ __align__(16) float lds[14720];   // 58880 B

    const int wave = threadIdx.x >> 6;
    const int lane = threadIdx.x & 63;
    const int g0   = blockIdx.x * 8;
    const int gl   = lane >> 3;
    const int mu   = lane & 7;
    const int g    = g0 + gl;
    const int gl3  = gl * 3;

    if (wave == 0) {
        // ===== DMA producer: r9 verbatim =====
        const float* pp = par + (size_t)g * 88 + mu;
        int xl = lane; if (xl >= 24) xl -= 24; if (xl >= 24) xl -= 24;
        const int xq = xl / 3;
        const float* px = x + (g0 + xq) * 3 + (xl - xq * 3);

        #pragma unroll
        for (int j = 0; j < 5; ++j)
            issue_slot(pp, px, j, lds + j * RAW_SLOT);

        for (int i = 0; i < 75; ++i) {
            if (i <= 71) {
                const int b = i + 1;                   // batches 1..72
                float* dst = lds + (b & 3) * RAW_REG;
                const int tb = 5 * b;
                #pragma unroll
                for (int j = 0; j < 5; ++j)
                    issue_slot(pp, px, tb + j, dst + j * RAW_SLOT);
                asm volatile("s_waitcnt vmcnt(30)" ::: "memory");
            } else {
                asm volatile("s_waitcnt vmcnt(0)" ::: "memory");
            }
            asm volatile("s_barrier" ::: "memory");
        }
    } else if (wave == 1) {
        // ===== transform wave: r9 body, 5-row output (hmean replaces inv_uzsum) =====
        const float* ps = par + ((size_t)(NSTEP - 1) * NGRID + g) * 88 + mu;
        const float f3   = 0.005f + ps[6 * 8] * 0.99f;
        const float f4   = 0.005f + ps[7 * 8] * 0.99f;
        const float klzp = ps[9 * 8];
        const float klzs = ps[10 * 8];

        for (int i = 0; i < 75; ++i) {
            if (i >= 1 && i <= 73) {
                const int b = i - 1;                   // batches 0..72
                const float* rreg = lds + (b & 3) * RAW_REG;
                float* dregf = lds + DER_BASE + (b & 1) * DER_REG;
                #pragma unroll
                for (int j = 0; j < 5; ++j) {
                    const float* rb = rreg + j * RAW_SLOT;
                    float2* db = reinterpret_cast<float2*>(dregf + j * DER_SLOT);
                    const float c1 = rb[64 + lane];
                    const float c2 = rb[128 + lane];
                    const float c3 = rb[192 + lane];
                    const float smaxv = 1.0f + c1 * 1999.0f;
                    const float f1 = 0.005f + c2 * 0.99f;
                    const float f2 = 0.005f + c3 * 0.99f;
                    const float uztwm = f1 * smaxv;
                    float rem = smaxv - uztwm;
                    const float uzfwm = fmaxf(CAPMIN, f2 * rem);
                    rem -= uzfwm;
                    const float lztwm = fmaxf(CAPMIN, f3 * rem);
                    rem -= lztwm;
                    const float lzfwpm = fmaxf(CAPMIN, f4 * rem);
                    const float lzfwsm = fmaxf(CAPMIN, (1.0f - f4) * rem);
                    const float pbase = lzfwpm * klzp + lzfwsm * klzs;
                    const float pz = fminf(lztwm + lzfwsm * (1.0f - klzs)
                                           + lzfwpm * (1.0f - klzp),
                                           100000.0f * pbase);
                    const float inv_uztwm = frcp(uztwm);
                    const float inv_uzfwm = frcp(uzfwm);
                    const float inv_lztwm = frcp(lztwm);
                    const float hmean = uztwm * uzfwm * frcp(uztwm + uzfwm);
                    const float inv_defmax = frcp(lztwm + lzfwpm + lzfwsm);
                    db[0 * 64 + lane] = make_float2(inv_uztwm, inv_uzfwm);
                    db[1 * 64 + lane] = make_float2(hmean, lztwm);
                    db[2 * 64 + lane] = make_float2(inv_lztwm, pbase);
                    db[3 * 64 + lane] = make_float2(lzfwpm, lzfwsm);
                    db[4 * 64 + lane] = make_float2(pz, inv_defmax);
                }
                asm volatile("s_waitcnt lgkmcnt(0)" ::: "memory");
            }
            asm volatile("s_barrier" ::: "memory");
        }
    } else {
        // ===== state wave: slim recurrence + reduction (r9 placement) =====
        const float* ps = par + ((size_t)(NSTEP - 1) * NGRID + g) * 88 + mu;
        const float e1    = 1.0f + ps[5 * 8] * 7.0f;
        const float pfree = ps[8 * 8];
        const float klzp  = ps[9 * 8];
        const float klzs  = ps[10 * 8];
        const float pfree1m = 1.0f - pfree;

        float S1 = 0.001f, S2 = 0.001f, S3 = 0.001f, S4 = 0.001f, S5 = 0.001f;
        float* smq = lds + SMQ_BASE;
        float* sme = lds + SME_BASE;

        for (int i = 0; i < 75; ++i) {
            if (i >= 2) {
                const int b = i - 2;                   // batches 0..72
                const float* rreg = lds + (b & 3) * RAW_REG;
                const float2* dreg = reinterpret_cast<const float2*>(
                    lds + DER_BASE + (b & 1) * DER_REG);

                RDS(0) RDS(1) RDS(2) RDS(3) RDS(4)
                STEP(0); STEP(1); STEP(2); STEP(3); STEP(4);

                if (lane < 40) {
                    const int s  = lane >> 3;
                    const int gg = lane & 7;
                    const float4* q4 = reinterpret_cast<const float4*>(&smq[s * 64 + gg * 8]);
                    const float4* e4 = reinterpret_cast<const float4*>(&sme[s * 64 + gg * 8]);
                    const float4 qa = q4[0], qb = q4[1];
                    const float4 ea = e4[0], eb = e4[1];
                    const float qsum = ((qa.x + qa.y) + (qa.z + qa.w))
                                     + ((qb.x + qb.y) + (qb.z + qb.w));
                    const float esum = ((ea.x + ea.y) + (ea.z + ea.w))
                                     + ((eb.x + eb.y) + (eb.z + eb.w));
                    float2 o = make_float2(qsum * 0.125f, esum * 0.125f);
                    *reinterpret_cast<float2*>(
                        out + ((size_t)(5 * b + s) * NGRID + g0 + gg) * 2) = o;
                }
            }
            asm volatile("s_barrier" ::: "memory");
        }
    }
}

extern "C" void kernel_launch(void* const* d_in, const int* in_sizes, int n_in,
                              void* d_out, int out_size, void* d_ws, size_t ws_size,
                              hipStream_t stream) {
    const float* x   = (const float*)d_in[0];   // (365, 4000, 3)
    const float* par = (const float*)d_in[1];   // (365, 4000, 11, 8)
    float* out = (float*)d_out;                 // (365, 4000, 2)

    sacsma_kernel<<<NGRID / 8, 192, 0, stream>>>(x, par, out);  // 500 WGs x 3 waves
}